// Round 1
// baseline (552.733 us; speedup 1.0000x reference)
//
#include <hip/hip_runtime.h>
#include <cstdint>

#define T_    15
#define C1    6
#define Hh    160
#define Ww    160
#define F1    30
#define THR1  15.0f
#define F2    250
#define THR2  10.0f
#define HP    80
#define WP    80
#define NLOC  6400          // 80*80
#define KWTA  8
#define P1R   164
#define P1S   (164*164)     // padded data map (pad 2)
#define P2R   84
#define P2S   (84*84)       // padded pooled map (pad 1, rounded to 84 for float4 align)
#define POT_OFF 24000000    // d_out: [0,24M) spike2, [24M,48M) pot2, [48M,48M+24) winners
#define WIN_OFF 48000000

// ---------- pad input data by 2 into P1 (zero-memset beforehand) ----------
__global__ void k_pad(const float* __restrict__ data, float* __restrict__ P1) {
    int idx = blockIdx.x * 256 + threadIdx.x;            // 15*6*160*160 = 2,304,000 exact
    int x = idx % 160;
    int y = (idx / 160) % 160;
    int tc = idx / 25600;                                // t*6+c
    P1[(size_t)tc * P1S + (size_t)(y + 2) * P1R + (x + 2)] = data[idx];
}

// ---------- conv1 (5x5) + fire(15) + maxpool 2x2 -> P2 (padded by 1) ----------
// block 256 = 4 waves; wave w handles feature f = by*4+w; lane: py(0..15), pxg(0..3)
// thread computes 2 conv rows x 8 conv cols -> 4 pooled outputs
__global__ __launch_bounds__(256) void k_conv1(const float* __restrict__ P1,
                                               const float* __restrict__ W1,
                                               float* __restrict__ P2) {
    int lane = threadIdx.x & 63;
    int wv   = __builtin_amdgcn_readfirstlane(threadIdx.x >> 6);
    int f    = blockIdx.y * 4 + wv;                      // 0..31 (mask f<30)
    int fw   = f < F1 ? f : F1 - 1;
    int ty   = blockIdx.x / 5, tx = blockIdx.x % 5;
    int t    = blockIdx.z;
    int py   = lane >> 2, pxg = lane & 3;
    int rowb = 32 * ty + 2 * py;                         // conv row base (padded coords)
    int cb   = 32 * tx + 8 * pxg;                        // input col base (16B aligned)
    const float* p1 = P1 + (size_t)(t * C1) * P1S;

    float a0[8], a1[8];
    #pragma unroll
    for (int i = 0; i < 8; i++) { a0[i] = 0.f; a1[i] = 0.f; }

    for (int c = 0; c < C1; c++) {
        const float* pc = p1 + (size_t)c * P1S;
        const float* wc = W1 + (fw * C1 + c) * 25;
        #pragma unroll
        for (int r = 0; r < 6; r++) {                    // input rows rowb..rowb+5
            const float4* rp = (const float4*)(pc + (size_t)(rowb + r) * P1R + cb);
            float4 u0 = rp[0], u1 = rp[1], u2 = rp[2];
            float d[12] = {u0.x,u0.y,u0.z,u0.w, u1.x,u1.y,u1.z,u1.w, u2.x,u2.y,u2.z,u2.w};
            if (r <= 4) {                                // sy=0, ky=r
                #pragma unroll
                for (int kx = 0; kx < 5; kx++) {
                    float w = wc[r * 5 + kx];
                    #pragma unroll
                    for (int cc = 0; cc < 8; cc++) a0[cc] += w * d[cc + kx];
                }
            }
            if (r >= 1) {                                // sy=1, ky=r-1
                #pragma unroll
                for (int kx = 0; kx < 5; kx++) {
                    float w = wc[(r - 1) * 5 + kx];
                    #pragma unroll
                    for (int cc = 0; cc < 8; cc++) a1[cc] += w * d[cc + kx];
                }
            }
        }
    }
    if (f < F1) {
        float* p2 = P2 + (size_t)(t * F1 + f) * P2S;
        int prow = 1 + 16 * ty + py;
        int pcol = 1 + 16 * tx + 4 * pxg;
        #pragma unroll
        for (int q = 0; q < 4; q++) {
            bool s = (a0[2*q] > THR1) || (a0[2*q+1] > THR1) ||
                     (a1[2*q] > THR1) || (a1[2*q+1] > THR1);
            p2[(size_t)prow * P2R + pcol + q] = s ? 1.0f : 0.0f;
        }
    }
}

// ---------- conv2 (3x3 over 30ch) + fire(10) -> pot_raw (d_out pot2 region) ----------
// block 256 = 4 waves; wave w: features f0=by*16+w*4 .. +3; lane: py(0..15), pxg(0..3)
// thread: 1 out row x 4 out cols x 4 features (16 acc)
__global__ __launch_bounds__(256) void k_conv2(const float* __restrict__ P2,
                                               const float* __restrict__ W2,
                                               float* __restrict__ pot) {
    int lane = threadIdx.x & 63;
    int wv   = __builtin_amdgcn_readfirstlane(threadIdx.x >> 6);
    int f0   = blockIdx.y * 16 + wv * 4;
    int ty   = blockIdx.x / 5, tx = blockIdx.x % 5;
    int t    = blockIdx.z;
    int py   = lane >> 2, pxg = lane & 3;
    int row  = 16 * ty + py;                             // out row
    int cx   = 16 * tx + 4 * pxg;                        // out col base (16B aligned)
    const float* pin = P2 + (size_t)(t * F1) * P2S;

    int fw0 = min(f0 + 0, F2 - 1), fw1 = min(f0 + 1, F2 - 1);
    int fw2 = min(f0 + 2, F2 - 1), fw3 = min(f0 + 3, F2 - 1);

    float4 acc0 = {0,0,0,0}, acc1 = {0,0,0,0}, acc2 = {0,0,0,0}, acc3 = {0,0,0,0};

    for (int c = 0; c < F1; c++) {
        const float* pc = pin + (size_t)c * P2S;
        const float* w0p = W2 + (fw0 * F1 + c) * 9;
        const float* w1p = W2 + (fw1 * F1 + c) * 9;
        const float* w2p = W2 + (fw2 * F1 + c) * 9;
        const float* w3p = W2 + (fw3 * F1 + c) * 9;
        #pragma unroll
        for (int ky = 0; ky < 3; ky++) {
            const float4* rp = (const float4*)(pc + (size_t)(row + ky) * P2R + cx);
            float4 u0 = rp[0], u1 = rp[1];
            float d[8] = {u0.x,u0.y,u0.z,u0.w, u1.x,u1.y,u1.z,u1.w};
            #pragma unroll
            for (int kx = 0; kx < 3; kx++) {
                float w0 = w0p[ky*3+kx], w1 = w1p[ky*3+kx];
                float w2 = w2p[ky*3+kx], w3 = w3p[ky*3+kx];
                float d0 = d[kx], d1 = d[kx+1], d2 = d[kx+2], d3 = d[kx+3];
                acc0.x += w0*d0; acc0.y += w0*d1; acc0.z += w0*d2; acc0.w += w0*d3;
                acc1.x += w1*d0; acc1.y += w1*d1; acc1.z += w1*d2; acc1.w += w1*d3;
                acc2.x += w2*d0; acc2.y += w2*d1; acc2.z += w2*d2; acc2.w += w2*d3;
                acc3.x += w3*d0; acc3.y += w3*d1; acc3.z += w3*d2; acc3.w += w3*d3;
            }
        }
    }
    float4 av[4] = {acc0, acc1, acc2, acc3};
    #pragma unroll
    for (int j = 0; j < 4; j++) {
        int f = f0 + j;
        if (f < F2) {
            float4 r;
            r.x = av[j].x > THR2 ? av[j].x : 0.f;
            r.y = av[j].y > THR2 ? av[j].y : 0.f;
            r.z = av[j].z > THR2 ? av[j].z : 0.f;
            r.w = av[j].w > THR2 ? av[j].w : 0.f;
            *(float4*)(pot + (size_t)(t * F2 + f) * NLOC + (size_t)row * WP + cx) = r;
        }
    }
}

// ---------- per-(t,loc) max/argmax over features ----------
__global__ void k_max(const float* __restrict__ pot,
                      float* __restrict__ maxv, int* __restrict__ maxi) {
    int idx = blockIdx.x * 256 + threadIdx.x;            // 15*6400 = 96,000 exact
    int loc = idx % NLOC;
    int t   = idx / NLOC;
    const float* p = pot + (size_t)t * F2 * NLOC + loc;
    float bv = p[0]; int bi = 0;
    #pragma unroll 5
    for (int f = 1; f < F2; f++) {
        float v = p[(size_t)f * NLOC];
        if (v > bv) { bv = v; bi = f; }                  // strict > : first-index argmax
    }
    maxv[idx] = bv; maxi[idx] = bi;
}

// ---------- per-loc inhibition winner + k-WTA per-location stats ----------
__global__ void k_inhib(const float* __restrict__ pot,
                        const float* __restrict__ maxv, const int* __restrict__ maxi,
                        int* __restrict__ winf, int* __restrict__ nsA,
                        float* __restrict__ vfA, unsigned* __restrict__ vmax) {
    int loc = blockIdx.x * 256 + threadIdx.x;            // 6400 exact
    float mv[T_]; int mi[T_];
    #pragma unroll
    for (int t = 0; t < T_; t++) { mv[t] = maxv[t * NLOC + loc]; mi[t] = maxi[t * NLOC + loc]; }
    int nclamp = 0;
    #pragma unroll
    for (int t = 0; t < T_; t++) nclamp += (mv[t] > 0.f);
    int ft = T_ - nclamp; if (ft > T_ - 1) ft = T_ - 1;  // first_t (clipped)
    int winner = -1;
    #pragma unroll
    for (int t = 0; t < T_; t++) if (t == ft) winner = mi[t];
    bool last = mv[T_ - 1] > 0.f;                        // clamp at final timestep
    if (!last) winner = -1;
    winf[loc] = winner;

    float col[T_];
    #pragma unroll
    for (int t = 0; t < T_; t++) col[t] = 0.f;
    if (winner >= 0) {
        const float* p = pot + (size_t)winner * NLOC + loc;
        #pragma unroll
        for (int t = 0; t < T_; t++) col[t] = p[(size_t)t * F2 * NLOC];
    }
    int ns = 0;
    #pragma unroll
    for (int t = 0; t < T_; t++) ns += (col[t] > 0.f);
    int f2 = T_ - ns; if (f2 > T_ - 1) f2 = T_ - 1;
    float vf = 0.f;
    #pragma unroll
    for (int t = 0; t < T_; t++) if (t == f2) vf = col[t];
    nsA[loc] = ns; vfA[loc] = vf;
    atomicMax(vmax, __float_as_uint(vf));                // vf >= 0 -> uint order ok
}

// ---------- apply inhibition in place + write spike2 ----------
__global__ void k_rewrite(float* __restrict__ outbuf, const int* __restrict__ winf) {
    int idx = blockIdx.x * 256 + threadIdx.x;            // 6,000,000 (float4 granules)
    if (idx >= T_ * F2 * (NLOC / 4)) return;
    int l4 = idx % (NLOC / 4);
    int f  = (idx / (NLOC / 4)) % F2;
    int t  = idx / ((NLOC / 4) * F2);
    int loc = l4 * 4;
    size_t off = (size_t)(t * F2 + f) * NLOC + loc;
    float4 pr = *(const float4*)(outbuf + POT_OFF + off);
    int4 wf = *(const int4*)(winf + loc);
    float4 po, sp;
    po.x = (wf.x == f) ? pr.x : 0.f;  sp.x = po.x > 0.f ? 1.f : 0.f;
    po.y = (wf.y == f) ? pr.y : 0.f;  sp.y = po.y > 0.f ? 1.f : 0.f;
    po.z = (wf.z == f) ? pr.z : 0.f;  sp.z = po.z > 0.f ? 1.f : 0.f;
    po.w = (wf.w == f) ? pr.w : 0.f;  sp.w = po.w > 0.f ? 1.f : 0.f;
    *(float4*)(outbuf + POT_OFF + off) = po;
    *(float4*)(outbuf + off) = sp;
}

// ---------- greedy k-WTA over compacted (one feature per loc) totals ----------
__global__ __launch_bounds__(256) void k_winners(const int* __restrict__ winf,
                                                 const int* __restrict__ nsA,
                                                 const float* __restrict__ vfA,
                                                 const unsigned* __restrict__ vmax,
                                                 float* __restrict__ wout) {
    __shared__ float tot[NLOC];
    __shared__ int   wfl[NLOC];
    __shared__ float rv[256];
    __shared__ int   rk[256];
    __shared__ float bvS; __shared__ int fiS, hiS, wiS;
    int tid = threadIdx.x;
    float v = __uint_as_float(vmax[0]) * (float)T_;
    for (int l = tid; l < NLOC; l += 256) {
        tot[l] = (float)nsA[l] * (vfA[l] + v);           // ns==0 -> 0
        wfl[l] = winf[l];
    }
    __syncthreads();
    for (int it = 0; it < KWTA; it++) {
        float bv = 0.f; int bk = 0x7fffffff;
        #pragma unroll
        for (int i = 0; i < 25; i++) {
            int l = tid * 25 + i;
            float vv = tot[l];
            int k = wfl[l] * NLOC + l;                   // flattened (f,h,w) index
            if (vv > bv || (vv == bv && k < bk)) { bv = vv; bk = k; }
        }
        rv[tid] = bv; rk[tid] = bk;
        __syncthreads();
        for (int s = 128; s > 0; s >>= 1) {
            if (tid < s) {
                float v2 = rv[tid + s]; int k2 = rk[tid + s];
                if (v2 > rv[tid] || (v2 == rv[tid] && k2 < rk[tid])) { rv[tid] = v2; rk[tid] = k2; }
            }
            __syncthreads();
        }
        if (tid == 0) {
            float bvv = rv[0]; int bkk = rk[0];
            bool valid = bvv > 0.f;
            int fi = valid ? bkk / NLOC : -1;
            int lc = bkk % NLOC;
            int hi = valid ? lc / WP : -1;
            int wi = valid ? lc % WP : -1;
            wout[it * 3 + 0] = (float)fi;
            wout[it * 3 + 1] = (float)hi;
            wout[it * 3 + 2] = (float)wi;
            bvS = bvv; fiS = fi; hiS = hi; wiS = wi;
        }
        __syncthreads();
        if (bvS > 0.f) {
            #pragma unroll
            for (int i = 0; i < 25; i++) {
                int l = tid * 25 + i;
                int h = l / WP, w = l % WP;
                bool kill = (wfl[l] == fiS) ||
                            (h >= hiS - 1 && h <= hiS + 1 && w >= wiS - 1 && w <= wiS + 1);
                if (kill) tot[l] = 0.f;
            }
        }
        __syncthreads();
    }
}

extern "C" void kernel_launch(void* const* d_in, const int* in_sizes, int n_in,
                              void* d_out, int out_size, void* d_ws, size_t ws_size,
                              hipStream_t stream) {
    const float* data = (const float*)d_in[0];
    const float* W1   = (const float*)d_in[1];
    const float* W2   = (const float*)d_in[2];
    float* out = (float*)d_out;
    float* ws  = (float*)d_ws;

    // ws layout (floats): P1[2,420,640] P2[3,175,200] maxv[96000] maxi[96000]
    //                     winf[6400] ns[6400] vf[6400] vmax[1]   -> 23.2 MB total
    float*    P1   = ws;
    float*    P2   = ws + 2420640;
    float*    maxv = ws + 5595840;
    int*      maxi = (int*)(ws + 5691840);
    int*      winf = (int*)(ws + 5787840);
    int*      nsA  = (int*)(ws + 5794240);
    float*    vfA  = ws + 5800640;
    unsigned* vmax = (unsigned*)(ws + 5807040);

    hipMemsetAsync(P1, 0, 2420640 * sizeof(float), stream);   // zero padding borders
    hipMemsetAsync(P2, 0, 3175200 * sizeof(float), stream);
    hipMemsetAsync(vmax, 0, sizeof(unsigned), stream);

    k_pad    <<<9000, 256, 0, stream>>>(data, P1);
    k_conv1  <<<dim3(25, 8, T_), 256, 0, stream>>>(P1, W1, P2);
    k_conv2  <<<dim3(25, 16, T_), 256, 0, stream>>>(P2, W2, out + POT_OFF);
    k_max    <<<375, 256, 0, stream>>>(out + POT_OFF, maxv, maxi);
    k_inhib  <<<25, 256, 0, stream>>>(out + POT_OFF, maxv, maxi, winf, nsA, vfA, vmax);
    k_rewrite<<<(T_ * F2 * (NLOC / 4) + 255) / 256, 256, 0, stream>>>(out, winf);
    k_winners<<<1, 256, 0, stream>>>(winf, nsA, vfA, vmax, out + WIN_OFF);
}

// Round 2
// 455.773 us; speedup vs baseline: 1.2127x; 1.2127x over previous
//
#include <hip/hip_runtime.h>
#include <cstdint>

#define T_    15
#define C1    6
#define F1    30
#define THR1  15.0f
#define F2    250
#define THR2  10.0f
#define WP    80
#define NLOC  6400          // 80*80
#define KWTA  8
#define P1R   164
#define P1S   (164*164)     // padded data map (pad 2)
#define P2R   84
#define P2S   (84*84)       // padded pooled map (pad 1, rounded to 84 for float4 align)
#define POT_OFF 24000000    // d_out: [0,24M) spike2, [24M,48M) pot2, [48M,48M+24) winners
#define WIN_OFF 48000000

typedef unsigned long long u64;

// ---------- pad input data by 2 into P1 (zero-memset beforehand) ----------
__global__ void k_pad(const float* __restrict__ data, float* __restrict__ P1) {
    int idx = blockIdx.x * 256 + threadIdx.x;            // 15*6*160*160 = 2,304,000 exact
    int x = idx % 160;
    int y = (idx / 160) % 160;
    int tc = idx / 25600;                                // t*6+c
    P1[(size_t)tc * P1S + (size_t)(y + 2) * P1R + (x + 2)] = data[idx];
}

// ---------- conv1 (5x5) + fire(15) + maxpool 2x2 -> P2 (padded by 1) ----------
__global__ __launch_bounds__(256) void k_conv1(const float* __restrict__ P1,
                                               const float* __restrict__ W1,
                                               float* __restrict__ P2) {
    int lane = threadIdx.x & 63;
    int wv   = __builtin_amdgcn_readfirstlane(threadIdx.x >> 6);
    int f    = blockIdx.y * 4 + wv;                      // 0..31 (mask f<30)
    int fw   = f < F1 ? f : F1 - 1;
    int ty   = blockIdx.x / 5, tx = blockIdx.x % 5;
    int t    = blockIdx.z;
    int py   = lane >> 2, pxg = lane & 3;
    int rowb = 32 * ty + 2 * py;
    int cb   = 32 * tx + 8 * pxg;
    const float* p1 = P1 + (size_t)(t * C1) * P1S;

    float a0[8], a1[8];
    #pragma unroll
    for (int i = 0; i < 8; i++) { a0[i] = 0.f; a1[i] = 0.f; }

    for (int c = 0; c < C1; c++) {
        const float* pc = p1 + (size_t)c * P1S;
        const float* wc = W1 + (fw * C1 + c) * 25;
        #pragma unroll
        for (int r = 0; r < 6; r++) {
            const float4* rp = (const float4*)(pc + (size_t)(rowb + r) * P1R + cb);
            float4 u0 = rp[0], u1 = rp[1], u2 = rp[2];
            float d[12] = {u0.x,u0.y,u0.z,u0.w, u1.x,u1.y,u1.z,u1.w, u2.x,u2.y,u2.z,u2.w};
            if (r <= 4) {
                #pragma unroll
                for (int kx = 0; kx < 5; kx++) {
                    float w = wc[r * 5 + kx];
                    #pragma unroll
                    for (int cc = 0; cc < 8; cc++) a0[cc] += w * d[cc + kx];
                }
            }
            if (r >= 1) {
                #pragma unroll
                for (int kx = 0; kx < 5; kx++) {
                    float w = wc[(r - 1) * 5 + kx];
                    #pragma unroll
                    for (int cc = 0; cc < 8; cc++) a1[cc] += w * d[cc + kx];
                }
            }
        }
    }
    if (f < F1) {
        float* p2 = P2 + (size_t)(t * F1 + f) * P2S;
        int prow = 1 + 16 * ty + py;
        int pcol = 1 + 16 * tx + 4 * pxg;
        #pragma unroll
        for (int q = 0; q < 4; q++) {
            bool s = (a0[2*q] > THR1) || (a0[2*q+1] > THR1) ||
                     (a1[2*q] > THR1) || (a1[2*q+1] > THR1);
            p2[(size_t)prow * P2R + pcol + q] = s ? 1.0f : 0.0f;
        }
    }
}

// ---------- transpose W2 [250][30][9] -> W2T [30*9][256] (pad f with 0) ----------
__global__ void k_wprep(const float* __restrict__ W2, float* __restrict__ W2T) {
    int f   = threadIdx.x;                               // 0..255
    int blk = blockIdx.x;                                // c*9+k, 0..269
    W2T[blk * 256 + f] = (f < F2) ? W2[f * 270 + blk] : 0.f;
}

// ---------- conv2 (3x3 over 30ch) + fire(10) -> dense pot + per-group argmax keys ----
// block 256 = 4 waves; wave wv: features f0=by*32+wv*8 .. +7; lane: py(0..15), pxg(0..3)
// thread: 1 out row x 4 out cols x 8 features (32 acc). 288 FMA per c-iter : 6 loads.
__global__ __launch_bounds__(256) void k_conv2max(const float* __restrict__ P2,
                                                  const float* __restrict__ W2T,
                                                  float* __restrict__ pot,
                                                  u64* __restrict__ gkey) {
    __shared__ u64 skey[4 * 256];
    int lane = threadIdx.x & 63;
    int wv   = __builtin_amdgcn_readfirstlane(threadIdx.x >> 6);
    int f0   = blockIdx.y * 32 + wv * 8;                 // wave-uniform
    int ty   = blockIdx.x / 5, tx = blockIdx.x % 5;
    int t    = blockIdx.z;
    int py   = lane >> 2, pxg = lane & 3;
    int row  = 16 * ty + py;
    int cx   = 16 * tx + 4 * pxg;
    const float* pin = P2 + (size_t)(t * F1) * P2S;

    float acc[8][4];
    #pragma unroll
    for (int j = 0; j < 8; j++)
        #pragma unroll
        for (int q = 0; q < 4; q++) acc[j][q] = 0.f;

    for (int c = 0; c < F1; c++) {
        const float* pc = pin + (size_t)c * P2S;
        const float* wb = W2T + (size_t)(c * 9) * 256 + f0;   // uniform -> s_loads
        #pragma unroll
        for (int ky = 0; ky < 3; ky++) {
            const float4* rp = (const float4*)(pc + (size_t)(row + ky) * P2R + cx);
            float4 u0 = rp[0], u1 = rp[1];
            float d[8] = {u0.x,u0.y,u0.z,u0.w, u1.x,u1.y,u1.z,u1.w};
            #pragma unroll
            for (int kx = 0; kx < 3; kx++) {
                const float* wp = wb + (ky * 3 + kx) * 256;
                #pragma unroll
                for (int j = 0; j < 8; j++) {
                    float w = wp[j];
                    acc[j][0] += w * d[kx + 0];
                    acc[j][1] += w * d[kx + 1];
                    acc[j][2] += w * d[kx + 2];
                    acc[j][3] += w * d[kx + 3];
                }
            }
        }
    }

    // fire + dense pot store + per-thread 8-feature argmax (key = valbits<<32 | 255-f)
    u64 best[4] = {0, 0, 0, 0};
    #pragma unroll
    for (int j = 0; j < 8; j++) {
        int f = f0 + j;
        float4 r;
        r.x = acc[j][0] > THR2 ? acc[j][0] : 0.f;
        r.y = acc[j][1] > THR2 ? acc[j][1] : 0.f;
        r.z = acc[j][2] > THR2 ? acc[j][2] : 0.f;
        r.w = acc[j][3] > THR2 ? acc[j][3] : 0.f;
        if (f < F2)
            *(float4*)(pot + ((size_t)t * F2 + f) * NLOC + (size_t)row * WP + cx) = r;
        // padded f>=250 have zero weights -> r=0, key low bits 255-f<=5 lose all ties
        u64 lo = (u64)(unsigned)(255 - f);
        u64 k0 = ((u64)__float_as_uint(r.x) << 32) | lo;
        u64 k1 = ((u64)__float_as_uint(r.y) << 32) | lo;
        u64 k2 = ((u64)__float_as_uint(r.z) << 32) | lo;
        u64 k3 = ((u64)__float_as_uint(r.w) << 32) | lo;
        best[0] = best[0] > k0 ? best[0] : k0;
        best[1] = best[1] > k1 ? best[1] : k1;
        best[2] = best[2] > k2 ? best[2] : k2;
        best[3] = best[3] > k3 ? best[3] : k3;
    }
    int sb = py * 16 + pxg * 4;
    #pragma unroll
    for (int q = 0; q < 4; q++) skey[wv * 256 + sb + q] = best[q];
    __syncthreads();
    int tid = threadIdx.x;
    u64 k0 = skey[tid], k1 = skey[256 + tid], k2 = skey[512 + tid], k3 = skey[768 + tid];
    u64 ka = k0 > k1 ? k0 : k1;
    u64 kb = k2 > k3 ? k2 : k3;
    u64 kk = ka > kb ? ka : kb;
    int r = tid >> 4, cc = tid & 15;
    gkey[(size_t)(blockIdx.y * T_ + t) * NLOC + (size_t)(16 * ty + r) * WP + 16 * tx + cc] = kk;
}

// ---------- per-loc: reduce 8 group keys/t, winner logic, gather winner column ----------
__global__ void k_red(const u64* __restrict__ gkey, const float* __restrict__ pot,
                      int* __restrict__ winf, int* __restrict__ nsA,
                      float* __restrict__ vfA, float* __restrict__ colv,
                      unsigned* __restrict__ vmax) {
    int loc = blockIdx.x * 256 + threadIdx.x;            // 6400 exact
    float mv[T_]; int mi[T_];
    #pragma unroll
    for (int t = 0; t < T_; t++) {
        u64 best = 0;
        #pragma unroll
        for (int g = 0; g < 8; g++) {
            u64 k = gkey[(size_t)(g * T_ + t) * NLOC + loc];
            best = best > k ? best : k;
        }
        mv[t] = __uint_as_float((unsigned)(best >> 32));
        mi[t] = 255 - (int)(best & 0xFFFFFFFFu);
    }
    int nclamp = 0;
    #pragma unroll
    for (int t = 0; t < T_; t++) nclamp += (mv[t] > 0.f);
    int ft = T_ - nclamp; if (ft > T_ - 1) ft = T_ - 1;
    int winner = -1;
    #pragma unroll
    for (int t = 0; t < T_; t++) if (t == ft) winner = mi[t];
    bool last = mv[T_ - 1] > 0.f;
    if (!last) winner = -1;
    winf[loc] = winner;

    float col[T_];
    #pragma unroll
    for (int t = 0; t < T_; t++) col[t] = 0.f;
    if (winner >= 0) {
        const float* p = pot + (size_t)winner * NLOC + loc;
        #pragma unroll
        for (int t = 0; t < T_; t++) col[t] = p[(size_t)t * F2 * NLOC];
    }
    int ns = 0;
    #pragma unroll
    for (int t = 0; t < T_; t++) ns += (col[t] > 0.f);
    int f2 = T_ - ns; if (f2 > T_ - 1) f2 = T_ - 1;
    float vf = 0.f;
    #pragma unroll
    for (int t = 0; t < T_; t++) if (t == f2) vf = col[t];
    nsA[loc] = ns; vfA[loc] = vf;
    #pragma unroll
    for (int t = 0; t < T_; t++) colv[t * NLOC + loc] = col[t];
    atomicMax(vmax, __float_as_uint(vf));
}

// ---------- write-only expansion: spike2 + inhibited pot2 from compact columns ----------
__global__ void k_zero(float* __restrict__ outbuf, const int* __restrict__ winf,
                       const float* __restrict__ colv) {
    int idx = blockIdx.x * 256 + threadIdx.x;            // T*F2*1600 = 6,000,000 granules
    if (idx >= T_ * F2 * (NLOC / 4)) return;
    int l4 = idx % (NLOC / 4);
    int f  = (idx / (NLOC / 4)) % F2;
    int t  = idx / ((NLOC / 4) * F2);
    int loc = l4 * 4;
    int4   wf = *(const int4*)(winf + loc);
    float4 cv = *(const float4*)(colv + t * NLOC + loc);
    float4 po, sp;
    po.x = (wf.x == f) ? cv.x : 0.f;  sp.x = po.x > 0.f ? 1.f : 0.f;
    po.y = (wf.y == f) ? cv.y : 0.f;  sp.y = po.y > 0.f ? 1.f : 0.f;
    po.z = (wf.z == f) ? cv.z : 0.f;  sp.z = po.z > 0.f ? 1.f : 0.f;
    po.w = (wf.w == f) ? cv.w : 0.f;  sp.w = po.w > 0.f ? 1.f : 0.f;
    size_t off = ((size_t)t * F2 + f) * NLOC + loc;
    *(float4*)(outbuf + POT_OFF + off) = po;
    *(float4*)(outbuf + off) = sp;
}

// ---------- greedy k-WTA over compacted (one feature per loc) totals ----------
__global__ __launch_bounds__(256) void k_winners(const int* __restrict__ winf,
                                                 const int* __restrict__ nsA,
                                                 const float* __restrict__ vfA,
                                                 const unsigned* __restrict__ vmax,
                                                 float* __restrict__ wout) {
    __shared__ float tot[NLOC];
    __shared__ int   wfl[NLOC];
    __shared__ float rv[256];
    __shared__ int   rk[256];
    __shared__ float bvS; __shared__ int fiS, hiS, wiS;
    int tid = threadIdx.x;
    float v = __uint_as_float(vmax[0]) * (float)T_;
    for (int l = tid; l < NLOC; l += 256) {
        tot[l] = (float)nsA[l] * (vfA[l] + v);           // ns==0 -> 0
        wfl[l] = winf[l];
    }
    __syncthreads();
    for (int it = 0; it < KWTA; it++) {
        float bv = 0.f; int bk = 0x7fffffff;
        #pragma unroll
        for (int i = 0; i < 25; i++) {
            int l = tid * 25 + i;
            float vv = tot[l];
            int k = wfl[l] * NLOC + l;
            if (vv > bv || (vv == bv && k < bk)) { bv = vv; bk = k; }
        }
        rv[tid] = bv; rk[tid] = bk;
        __syncthreads();
        for (int s = 128; s > 0; s >>= 1) {
            if (tid < s) {
                float v2 = rv[tid + s]; int k2 = rk[tid + s];
                if (v2 > rv[tid] || (v2 == rv[tid] && k2 < rk[tid])) { rv[tid] = v2; rk[tid] = k2; }
            }
            __syncthreads();
        }
        if (tid == 0) {
            float bvv = rv[0]; int bkk = rk[0];
            bool valid = bvv > 0.f;
            int fi = valid ? bkk / NLOC : -1;
            int lc = bkk % NLOC;
            int hi = valid ? lc / WP : -1;
            int wi = valid ? lc % WP : -1;
            wout[it * 3 + 0] = (float)fi;
            wout[it * 3 + 1] = (float)hi;
            wout[it * 3 + 2] = (float)wi;
            bvS = bvv; fiS = fi; hiS = hi; wiS = wi;
        }
        __syncthreads();
        if (bvS > 0.f) {
            #pragma unroll
            for (int i = 0; i < 25; i++) {
                int l = tid * 25 + i;
                int h = l / WP, w = l % WP;
                bool kill = (wfl[l] == fiS) ||
                            (h >= hiS - 1 && h <= hiS + 1 && w >= wiS - 1 && w <= wiS + 1);
                if (kill) tot[l] = 0.f;
            }
        }
        __syncthreads();
    }
}

extern "C" void kernel_launch(void* const* d_in, const int* in_sizes, int n_in,
                              void* d_out, int out_size, void* d_ws, size_t ws_size,
                              hipStream_t stream) {
    const float* data = (const float*)d_in[0];
    const float* W1   = (const float*)d_in[1];
    const float* W2   = (const float*)d_in[2];
    float* out = (float*)d_out;
    float* ws  = (float*)d_ws;

    // ws layout (floats): P1[2,420,640] P2[3,175,200] W2T[69,120]
    //                     winf[6400] ns[6400] vf[6400] colv[96,000] vmax[1]  -> 23.1 MB
    float*    P1   = ws;
    float*    P2   = ws + 2420640;
    float*    W2T  = ws + 5595840;
    int*      winf = (int*)(ws + 5664960);
    int*      nsA  = (int*)(ws + 5671360);
    float*    vfA  = ws + 5677760;
    float*    colv = ws + 5684160;
    unsigned* vmax = (unsigned*)(ws + 5780160);

    // gkey (8 groups x 15 t x 6400 u64 = 6.1 MB) lives in d_out's spike region,
    // which is overwritten densely by k_zero afterwards.
    u64* gkey = (u64*)d_out;
    float* potD = out + POT_OFF;   // dense fired pot, overwritten in place by k_zero

    hipMemsetAsync(P1, 0, 2420640 * sizeof(float), stream);   // zero padding borders
    hipMemsetAsync(P2, 0, 3175200 * sizeof(float), stream);
    hipMemsetAsync(vmax, 0, sizeof(unsigned), stream);

    k_pad     <<<9000, 256, 0, stream>>>(data, P1);
    k_conv1   <<<dim3(25, 8, T_), 256, 0, stream>>>(P1, W1, P2);
    k_wprep   <<<270, 256, 0, stream>>>(W2, W2T);
    k_conv2max<<<dim3(25, 8, T_), 256, 0, stream>>>(P2, W2T, potD, gkey);
    k_red     <<<25, 256, 0, stream>>>(gkey, potD, winf, nsA, vfA, colv, vmax);
    k_zero    <<<(T_ * F2 * (NLOC / 4) + 255) / 256, 256, 0, stream>>>(out, winf, colv);
    k_winners <<<1, 256, 0, stream>>>(winf, nsA, vfA, vmax, out + WIN_OFF);
}

// Round 3
// 410.147 us; speedup vs baseline: 1.3476x; 1.1112x over previous
//
#include <hip/hip_runtime.h>
#include <cstdint>

#define T_    15
#define C1    6
#define F1    30
#define THR1  15.0f
#define F2    250
#define THR2  10.0f
#define WP    80
#define NLOC  6400          // 80*80
#define KWTA  8
#define P1R   164
#define P1S   (164*164)     // padded data map (pad 2)
#define P2R   84
#define P2S   (84*84)       // padded pooled map (pad 1, rounded to 84 for float4 align)
#define POT_OFF 24000000    // d_out: [0,24M) spike2, [24M,48M) pot2, [48M,48M+24) winners
#define WIN_OFF 48000000

typedef unsigned long long u64;
typedef unsigned short u16;
typedef short s16x8 __attribute__((ext_vector_type(8)));
typedef float f32x4 __attribute__((ext_vector_type(4)));

static __device__ __forceinline__ u16 f2bf(float x) {      // RNE fp32->bf16
    unsigned u = __float_as_uint(x);
    return (u16)((u + 0x7FFF + ((u >> 16) & 1)) >> 16);
}
static __device__ __forceinline__ float bf2f(u16 h) {
    return __uint_as_float(((unsigned)h) << 16);
}

// ---------- pad input data by 2 into P1 (zero-memset beforehand) ----------
__global__ void k_pad(const float* __restrict__ data, float* __restrict__ P1) {
    int idx = blockIdx.x * 256 + threadIdx.x;            // 2,304,000 exact
    int x = idx % 160;
    int y = (idx / 160) % 160;
    int tc = idx / 25600;
    P1[(size_t)tc * P1S + (size_t)(y + 2) * P1R + (x + 2)] = data[idx];
}

// ---------- conv1 (5x5) + fire(15) + maxpool 2x2 -> P2 (padded by 1) ----------
__global__ __launch_bounds__(256) void k_conv1(const float* __restrict__ P1,
                                               const float* __restrict__ W1,
                                               float* __restrict__ P2) {
    int lane = threadIdx.x & 63;
    int wv   = __builtin_amdgcn_readfirstlane(threadIdx.x >> 6);
    int f    = blockIdx.y * 4 + wv;
    int fw   = f < F1 ? f : F1 - 1;
    int ty   = blockIdx.x / 5, tx = blockIdx.x % 5;
    int t    = blockIdx.z;
    int py   = lane >> 2, pxg = lane & 3;
    int rowb = 32 * ty + 2 * py;
    int cb   = 32 * tx + 8 * pxg;
    const float* p1 = P1 + (size_t)(t * C1) * P1S;

    float a0[8], a1[8];
    #pragma unroll
    for (int i = 0; i < 8; i++) { a0[i] = 0.f; a1[i] = 0.f; }

    for (int c = 0; c < C1; c++) {
        const float* pc = p1 + (size_t)c * P1S;
        const float* wc = W1 + (fw * C1 + c) * 25;
        #pragma unroll
        for (int r = 0; r < 6; r++) {
            const float4* rp = (const float4*)(pc + (size_t)(rowb + r) * P1R + cb);
            float4 u0 = rp[0], u1 = rp[1], u2 = rp[2];
            float d[12] = {u0.x,u0.y,u0.z,u0.w, u1.x,u1.y,u1.z,u1.w, u2.x,u2.y,u2.z,u2.w};
            if (r <= 4) {
                #pragma unroll
                for (int kx = 0; kx < 5; kx++) {
                    float w = wc[r * 5 + kx];
                    #pragma unroll
                    for (int cc = 0; cc < 8; cc++) a0[cc] += w * d[cc + kx];
                }
            }
            if (r >= 1) {
                #pragma unroll
                for (int kx = 0; kx < 5; kx++) {
                    float w = wc[(r - 1) * 5 + kx];
                    #pragma unroll
                    for (int cc = 0; cc < 8; cc++) a1[cc] += w * d[cc + kx];
                }
            }
        }
    }
    if (f < F1) {
        float* p2 = P2 + (size_t)(t * F1 + f) * P2S;
        int prow = 1 + 16 * ty + py;
        int pcol = 1 + 16 * tx + 4 * pxg;
        #pragma unroll
        for (int q = 0; q < 4; q++) {
            bool s = (a0[2*q] > THR1) || (a0[2*q+1] > THR1) ||
                     (a1[2*q] > THR1) || (a1[2*q+1] > THR1);
            p2[(size_t)prow * P2R + pcol + q] = s ? 1.0f : 0.0f;
        }
    }
}

// ---------- W2 -> bf16x3 split, MFMA A-frag layout ----------
// Wfrag elem E = (((s*9+g)*16 + ft)*64 + lane)*8 + j ; A[m=lane&15][k=(lane>>4)*8+j]
// f = ft*16 + (lane&15), c = k, g = ky*3+kx. f>=250 / c>=30 are zero pad.
__global__ void k_wprep(const float* __restrict__ W2, u16* __restrict__ Wf) {
    int E = blockIdx.x * 256 + threadIdx.x;              // 221,184 exact (864 blocks)
    int j    = E & 7;
    int lane = (E >> 3) & 63;
    int ft   = (E >> 9) & 15;
    int rest = E >> 13;                                  // 0..26
    int s = rest / 9, g = rest % 9;
    int c = (lane >> 4) * 8 + j;
    int f = ft * 16 + (lane & 15);
    float w = (c < F1 && f < F2) ? W2[f * 270 + c * 9 + g] : 0.f;
    u16 h = f2bf(w);          float fh = bf2f(h);
    u16 m = f2bf(w - fh);     float fm = bf2f(m);
    u16 l = f2bf(w - fh - fm);
    Wf[E] = (s == 0) ? h : (s == 1) ? m : l;
}

// ---------- conv2 via MFMA (bf16x3) + fused fire + per-(t,loc) argmax key ----------
// grid (100, 15): block tile = 256 f x (4 rows x 16 cols). wave = 64 f x 64 locs.
__global__ __launch_bounds__(256) void k_conv2m(const float* __restrict__ P2,
                                                const u16* __restrict__ Wf,
                                                u64* __restrict__ gkey) {
    __shared__ u16 rawT[6 * 18 * 32];                    // [r][col][c] bf16 input strip
    __shared__ u64 skey[4 * 4 * 16];                     // [wv][nt][n]
    int tid  = threadIdx.x;
    int lane = tid & 63;
    int wv   = __builtin_amdgcn_readfirstlane(tid >> 6);
    int bx   = blockIdx.x;
    int t    = blockIdx.y;
    int xt = bx % 5, yt = bx / 5;
    int y0 = yt * 4, x0 = xt * 16;

    // stage input strip (rows y0..y0+5, cols x0..x0+17, 30ch) as bf16 [r][col][c]
    for (int e = tid; e < 3456; e += 256) {
        int c = e / 108, rem = e % 108, r = rem / 18, col = rem % 18;
        float v = (c < F1)
            ? P2[(size_t)(t * F1 + c) * P2S + (size_t)(y0 + r) * P2R + (x0 + col)] : 0.f;
        rawT[(r * 18 + col) * 32 + c] = f2bf(v);
    }
    __syncthreads();

    int q = lane >> 4, n = lane & 15;
    f32x4 accA[4][4], accB[4][4];                        // [j(ftile)][nt] hi / mid+lo
    #pragma unroll
    for (int j = 0; j < 4; j++)
        #pragma unroll
        for (int nt = 0; nt < 4; nt++) { accA[j][nt] = (f32x4)0.f; accB[j][nt] = (f32x4)0.f; }

    #pragma unroll
    for (int ky = 0; ky < 3; ky++) {
        #pragma unroll
        for (int kx = 0; kx < 3; kx++) {
            int g = ky * 3 + kx;
            s16x8 bf[4];
            #pragma unroll
            for (int nt = 0; nt < 4; nt++)
                bf[nt] = *(const s16x8*)&rawT[((nt + ky) * 18 + (n + kx)) * 32 + q * 8];
            #pragma unroll
            for (int s = 0; s < 3; s++) {
                #pragma unroll
                for (int j = 0; j < 4; j++) {
                    s16x8 af = *(const s16x8*)&Wf[(size_t)((((s * 9 + g) * 16) + (wv * 4 + j)) * 64 + lane) * 8];
                    f32x4* accp = (s == 0) ? accA[j] : accB[j];
                    #pragma unroll
                    for (int nt = 0; nt < 4; nt++)
                        accp[nt] = __builtin_amdgcn_mfma_f32_16x16x32_bf16(af, bf[nt], accp[nt], 0, 0, 0);
                }
            }
        }
    }

    // epilogue: fire + key(val, 255-f), reduce 16 rows/lane, then q-lanes, then waves
    #pragma unroll
    for (int nt = 0; nt < 4; nt++) {
        u64 best = 0;
        #pragma unroll
        for (int j = 0; j < 4; j++) {
            #pragma unroll
            for (int r = 0; r < 4; r++) {
                float pot = accA[j][nt][r] + accB[j][nt][r];
                float rr  = pot > THR2 ? pot : 0.f;
                int f = (wv * 4 + j) * 16 + q * 4 + r;
                u64 key = ((u64)__float_as_uint(rr) << 32) | (u64)(unsigned)(255 - f);
                best = best > key ? best : key;
            }
        }
        u64 o = __shfl_xor(best, 16, 64); best = best > o ? best : o;
        o     = __shfl_xor(best, 32, 64); best = best > o ? best : o;
        if (q == 0) skey[(wv * 4 + nt) * 16 + n] = best;
    }
    __syncthreads();
    if (tid < 64) {
        int nt2 = tid >> 4, n2 = tid & 15;
        u64 b = skey[nt2 * 16 + n2];
        #pragma unroll
        for (int w = 1; w < 4; w++) {
            u64 k = skey[(w * 4 + nt2) * 16 + n2];
            b = b > k ? b : k;
        }
        gkey[(size_t)t * NLOC + (size_t)(y0 + nt2) * WP + (x0 + n2)] = b;
    }
}

// ---------- per-(t,loc): winner logic + exact fp32 recompute of winner column ----------
__global__ void k_col(const u64* __restrict__ gkey, const float* __restrict__ P2,
                      const float* __restrict__ W2, int* __restrict__ winf,
                      float* __restrict__ colv) {
    int idx = blockIdx.x * 256 + threadIdx.x;            // 96,000 exact
    int t   = idx / NLOC;
    int loc = idx % NLOC;
    float mv[T_]; int mi[T_];
    #pragma unroll
    for (int t2 = 0; t2 < T_; t2++) {
        u64 k = gkey[(size_t)t2 * NLOC + loc];
        mv[t2] = __uint_as_float((unsigned)(k >> 32));
        mi[t2] = 255 - (int)(k & 0xFFFFFFFFu);
    }
    int nclamp = 0;
    #pragma unroll
    for (int t2 = 0; t2 < T_; t2++) nclamp += (mv[t2] > 0.f);
    int ft = T_ - nclamp; if (ft > T_ - 1) ft = T_ - 1;
    int wf = -1;
    #pragma unroll
    for (int t2 = 0; t2 < T_; t2++) if (t2 == ft) wf = mi[t2];
    if (!(mv[T_ - 1] > 0.f)) wf = -1;
    if (t == 0) winf[loc] = wf;

    float acc = 0.f;
    if (wf >= 0) {
        int y = loc / WP, x = loc % WP;
        const float* pb = P2 + (size_t)(t * F1) * P2S + (size_t)y * P2R + x;
        const float* wb = W2 + wf * 270;
        for (int c = 0; c < F1; c++) {                   // same c,ky,kx order as R2 conv
            #pragma unroll
            for (int ky = 0; ky < 3; ky++)
                #pragma unroll
                for (int kx = 0; kx < 3; kx++)
                    acc += wb[c * 9 + ky * 3 + kx] * pb[(size_t)c * P2S + ky * P2R + kx];
    }
    }
    acc = acc > THR2 ? acc : 0.f;                        // fire
    colv[t * NLOC + loc] = acc;
}

// ---------- per-loc k-WTA stats from exact columns ----------
__global__ void k_stat(const float* __restrict__ colv, int* __restrict__ nsA,
                       float* __restrict__ vfA, unsigned* __restrict__ vmax) {
    int loc = blockIdx.x * 256 + threadIdx.x;            // 6400 exact
    float col[T_];
    #pragma unroll
    for (int t = 0; t < T_; t++) col[t] = colv[t * NLOC + loc];
    int ns = 0;
    #pragma unroll
    for (int t = 0; t < T_; t++) ns += (col[t] > 0.f);
    int f2 = T_ - ns; if (f2 > T_ - 1) f2 = T_ - 1;
    float vf = 0.f;
    #pragma unroll
    for (int t = 0; t < T_; t++) if (t == f2) vf = col[t];
    nsA[loc] = ns; vfA[loc] = vf;
    atomicMax(vmax, __float_as_uint(vf));
}

// ---------- write-only expansion: spike2 + inhibited pot2 from compact columns ----------
__global__ void k_zero(float* __restrict__ outbuf, const int* __restrict__ winf,
                       const float* __restrict__ colv) {
    int idx = blockIdx.x * 256 + threadIdx.x;
    if (idx >= T_ * F2 * (NLOC / 4)) return;
    int l4 = idx % (NLOC / 4);
    int f  = (idx / (NLOC / 4)) % F2;
    int t  = idx / ((NLOC / 4) * F2);
    int loc = l4 * 4;
    int4   wf = *(const int4*)(winf + loc);
    float4 cv = *(const float4*)(colv + t * NLOC + loc);
    float4 po, sp;
    po.x = (wf.x == f) ? cv.x : 0.f;  sp.x = po.x > 0.f ? 1.f : 0.f;
    po.y = (wf.y == f) ? cv.y : 0.f;  sp.y = po.y > 0.f ? 1.f : 0.f;
    po.z = (wf.z == f) ? cv.z : 0.f;  sp.z = po.z > 0.f ? 1.f : 0.f;
    po.w = (wf.w == f) ? cv.w : 0.f;  sp.w = po.w > 0.f ? 1.f : 0.f;
    size_t off = ((size_t)t * F2 + f) * NLOC + loc;
    *(float4*)(outbuf + POT_OFF + off) = po;
    *(float4*)(outbuf + off) = sp;
}

// ---------- greedy k-WTA over compacted (one feature per loc) totals ----------
__global__ __launch_bounds__(256) void k_winners(const int* __restrict__ winf,
                                                 const int* __restrict__ nsA,
                                                 const float* __restrict__ vfA,
                                                 const unsigned* __restrict__ vmax,
                                                 float* __restrict__ wout) {
    __shared__ float tot[NLOC];
    __shared__ int   wfl[NLOC];
    __shared__ float rv[256];
    __shared__ int   rk[256];
    __shared__ float bvS; __shared__ int fiS, hiS, wiS;
    int tid = threadIdx.x;
    float v = __uint_as_float(vmax[0]) * (float)T_;
    for (int l = tid; l < NLOC; l += 256) {
        tot[l] = (float)nsA[l] * (vfA[l] + v);
        wfl[l] = winf[l];
    }
    __syncthreads();
    for (int it = 0; it < KWTA; it++) {
        float bv = 0.f; int bk = 0x7fffffff;
        #pragma unroll
        for (int i = 0; i < 25; i++) {
            int l = tid * 25 + i;
            float vv = tot[l];
            int k = wfl[l] * NLOC + l;
            if (vv > bv || (vv == bv && k < bk)) { bv = vv; bk = k; }
        }
        rv[tid] = bv; rk[tid] = bk;
        __syncthreads();
        for (int s = 128; s > 0; s >>= 1) {
            if (tid < s) {
                float v2 = rv[tid + s]; int k2 = rk[tid + s];
                if (v2 > rv[tid] || (v2 == rv[tid] && k2 < rk[tid])) { rv[tid] = v2; rk[tid] = k2; }
            }
            __syncthreads();
        }
        if (tid == 0) {
            float bvv = rv[0]; int bkk = rk[0];
            bool valid = bvv > 0.f;
            int fi = valid ? bkk / NLOC : -1;
            int lc = bkk % NLOC;
            int hi = valid ? lc / WP : -1;
            int wi = valid ? lc % WP : -1;
            wout[it * 3 + 0] = (float)fi;
            wout[it * 3 + 1] = (float)hi;
            wout[it * 3 + 2] = (float)wi;
            bvS = bvv; fiS = fi; hiS = hi; wiS = wi;
        }
        __syncthreads();
        if (bvS > 0.f) {
            #pragma unroll
            for (int i = 0; i < 25; i++) {
                int l = tid * 25 + i;
                int h = l / WP, w = l % WP;
                bool kill = (wfl[l] == fiS) ||
                            (h >= hiS - 1 && h <= hiS + 1 && w >= wiS - 1 && w <= wiS + 1);
                if (kill) tot[l] = 0.f;
            }
        }
        __syncthreads();
    }
}

extern "C" void kernel_launch(void* const* d_in, const int* in_sizes, int n_in,
                              void* d_out, int out_size, void* d_ws, size_t ws_size,
                              hipStream_t stream) {
    const float* data = (const float*)d_in[0];
    const float* W1   = (const float*)d_in[1];
    const float* W2   = (const float*)d_in[2];
    float* out = (float*)d_out;
    float* ws  = (float*)d_ws;

    // ws layout (floats): P1[2,420,640] P2[3,175,200] Wfrag[110,592f = 221,184 u16]
    //                     winf[6400] ns[6400] vf[6400] colv[96,000] vmax[1]  -> 23.3 MB
    float*    P1   = ws;
    float*    P2   = ws + 2420640;
    u16*      Wf   = (u16*)(ws + 5595840);
    int*      winf = (int*)(ws + 5706432);
    int*      nsA  = (int*)(ws + 5712832);
    float*    vfA  = ws + 5719232;
    float*    colv = ws + 5725632;
    unsigned* vmax = (unsigned*)(ws + 5821632);

    // gkey (15 x 6400 u64 = 768 KB) lives in d_out's spike region (rewritten by k_zero)
    u64* gkey = (u64*)d_out;

    hipMemsetAsync(P1, 0, 2420640 * sizeof(float), stream);
    hipMemsetAsync(P2, 0, 3175200 * sizeof(float), stream);
    hipMemsetAsync(vmax, 0, sizeof(unsigned), stream);

    k_pad    <<<9000, 256, 0, stream>>>(data, P1);
    k_conv1  <<<dim3(25, 8, T_), 256, 0, stream>>>(P1, W1, P2);
    k_wprep  <<<864, 256, 0, stream>>>(W2, Wf);
    k_conv2m <<<dim3(100, T_), 256, 0, stream>>>(P2, Wf, gkey);
    k_col    <<<375, 256, 0, stream>>>(gkey, P2, W2, winf, colv);
    k_stat   <<<25, 256, 0, stream>>>(colv, nsA, vfA, vmax);
    k_zero   <<<(T_ * F2 * (NLOC / 4) + 255) / 256, 256, 0, stream>>>(out, winf, colv);
    k_winners<<<1, 256, 0, stream>>>(winf, nsA, vfA, vmax, out + WIN_OFF);
}